// Round 1
// baseline (833.650 us; speedup 1.0000x reference)
//
#include <hip/hip_runtime.h>
#include <hip/hip_bf16.h>
#include <stdint.h>
#include <stddef.h>

typedef unsigned short u16;
typedef __bf16 bf16x8 __attribute__((ext_vector_type(8)));
typedef float f32x4 __attribute__((ext_vector_type(4)));

#define NH 32
#define NKV 8
#define HD 128
#define QKV_N 6144
#define SEQ 2048

__device__ __forceinline__ u16 f2b(float x) {
  union { float f; unsigned u; } v; v.f = x;
  unsigned r = v.u + 0x7FFF + ((v.u >> 16) & 1);
  return (u16)(r >> 16);
}
__device__ __forceinline__ float b2f(u16 b) {
  union { float f; unsigned u; } v; v.u = ((unsigned)b) << 16;
  return v.f;
}
__device__ __forceinline__ void gload16(const void* g, void* l) {
  __builtin_amdgcn_global_load_lds((const __attribute__((address_space(1))) unsigned int*)g,
                                   (__attribute__((address_space(3))) unsigned int*)l, 16, 0, 0);
}

// ---------------- cast fp32 -> bf16 (vectorized) ----------------
__global__ void cast_f32_bf16(const float* __restrict__ in, u16* __restrict__ out, int n) {
  int i = (blockIdx.x * blockDim.x + threadIdx.x) * 4;
  if (i >= n) return;
  float4 v = *(const float4*)&in[i];
  ushort4 o;
  o.x = f2b(v.x); o.y = f2b(v.y); o.z = f2b(v.z); o.w = f2b(v.w);
  *(ushort4*)&out[i] = o;
}

// ---------- cast + transpose: in [K][N] fp32 -> out [N][K] bf16 ----------
__global__ void cast_transpose(const float* __restrict__ in, u16* __restrict__ out, int K, int N) {
  __shared__ float t[32][33];
  int n0 = blockIdx.x * 32, k0 = blockIdx.y * 32;
  int tx = threadIdx.x, ty = threadIdx.y;  // (32,8)
#pragma unroll
  for (int i = 0; i < 4; ++i)
    t[ty + i * 8][tx] = in[(size_t)(k0 + ty + i * 8) * N + n0 + tx];
  __syncthreads();
#pragma unroll
  for (int i = 0; i < 4; ++i)
    out[(size_t)(n0 + ty + i * 8) * K + k0 + tx] = f2b(t[tx][ty + i * 8]);
}

// ---------------- GEMM: C[M][N] = A[M][K] * Bt[N][K]^T (bf16 MFMA) ----------------
__device__ __forceinline__ void storeC(float* C, size_t i, float v) { C[i] = v; }
__device__ __forceinline__ void storeC(u16* C, size_t i, float v) { C[i] = f2b(v); }

template <typename OutT>
__global__ __launch_bounds__(256) void gemm_bt(const u16* __restrict__ A, const u16* __restrict__ Bt,
                                               OutT* __restrict__ C, int M, int N, int K) {
  __shared__ __align__(16) u16 sA[128 * 64];
  __shared__ __align__(16) u16 sB[128 * 64];
  const int nbx = N >> 7;
  const int nwg = (M >> 7) * nbx;
  const int cpx = nwg >> 3;  // nwg % 8 == 0 for our shapes
  const int wg = (blockIdx.x & 7) * cpx + (blockIdx.x >> 3);
  const int row0 = (wg / nbx) << 7;
  const int col0 = (wg % nbx) << 7;
  const int tid = threadIdx.x, w = tid >> 6, lane = tid & 63;
  const int wr = (w >> 1) * 64, wc = (w & 1) * 64;
  f32x4 acc[4][4] = {};
  for (int kt = 0; kt < K; kt += 64) {
    // stage 128x64 A-tile and B-tile (1024 granules of 16B each), source pre-swizzled
#pragma unroll
    for (int c = 0; c < 4; ++c) {
      const int g = c * 256 + w * 64 + lane;
      const int r = g >> 3, gc = g & 7;
      const int srcoff = kt + ((gc ^ (r & 7)) << 3);
      gload16(A + (size_t)(row0 + r) * K + srcoff, &sA[(c * 256 + w * 64) * 8]);
      gload16(Bt + (size_t)(col0 + r) * K + srcoff, &sB[(c * 256 + w * 64) * 8]);
    }
    __syncthreads();
#pragma unroll
    for (int ks = 0; ks < 2; ++ks) {
      bf16x8 a[4], b[4];
#pragma unroll
      for (int mi = 0; mi < 4; ++mi) {
        const int r = wr + mi * 16 + (lane & 15);
        const int g = (ks * 4 + (lane >> 4)) ^ (r & 7);
        a[mi] = *(const bf16x8*)&sA[r * 64 + g * 8];
      }
#pragma unroll
      for (int ni = 0; ni < 4; ++ni) {
        const int r = wc + ni * 16 + (lane & 15);
        const int g = (ks * 4 + (lane >> 4)) ^ (r & 7);
        b[ni] = *(const bf16x8*)&sB[r * 64 + g * 8];
      }
#pragma unroll
      for (int mi = 0; mi < 4; ++mi)
#pragma unroll
        for (int ni = 0; ni < 4; ++ni)
          acc[mi][ni] = __builtin_amdgcn_mfma_f32_16x16x32_bf16(a[mi], b[ni], acc[mi][ni], 0, 0, 0);
    }
    __syncthreads();
  }
#pragma unroll
  for (int mi = 0; mi < 4; ++mi)
#pragma unroll
    for (int ni = 0; ni < 4; ++ni)
#pragma unroll
      for (int j = 0; j < 4; ++j) {
        const int row = row0 + wr + mi * 16 + (lane >> 4) * 4 + j;
        const int col = col0 + wc + ni * 16 + (lane & 15);
        storeC(C, (size_t)row * N + col, acc[mi][ni][j]);
      }
}

// ---------------- RoPE (NeoX), in-place on qkv; folds scale*log2e into q ----------------
__global__ void rope_kernel(u16* __restrict__ qkv, const int* __restrict__ pos, float qscale) {
  __shared__ float cs[64], sn[64];
  const int row = blockIdx.x;  // 0..4095 = (b,s)
  const int tid = threadIdx.x;
  if (tid < 64) {
    float p = (float)pos[row];
    float inv = exp2f(-(float)tid * 0.20762050593046f);  // log2(10000)/64
    float a = p * inv;
    cs[tid] = cosf(a);
    sn[tid] = sinf(a);
  }
  __syncthreads();
  const size_t base = (size_t)row * QKV_N;
  for (int i = tid; i < 40 * 64; i += 256) {  // 32 q heads + 8 k heads
    const int h = i >> 6, d = i & 63;
    const size_t o = base + h * 128 + d;  // h>=32 lands in k region (4096..5119)
    float x1 = b2f(qkv[o]), x2 = b2f(qkv[o + 64]);
    float c = cs[d], s = sn[d];
    float o1 = x1 * c - x2 * s;
    float o2 = x2 * c + x1 * s;
    if (h < NH) { o1 *= qscale; o2 *= qscale; }
    qkv[o] = f2b(o1);
    qkv[o + 64] = f2b(o2);
  }
}

// ---------------- V transpose: qkv v-section -> vt[(b*8+kvh)*128 + d][2048] ----------------
__global__ void v_transpose(const u16* __restrict__ qkv, u16* __restrict__ vt) {
  __shared__ u16 t[32][33];
  const int b = blockIdx.z >> 3, kvh = blockIdx.z & 7;
  const int s0 = blockIdx.x * 32, d0 = blockIdx.y * 32;
  const int tx = threadIdx.x, ty = threadIdx.y;
#pragma unroll
  for (int i = 0; i < 4; ++i)
    t[ty + i * 8][tx] = qkv[(size_t)(b * SEQ + s0 + ty + i * 8) * QKV_N + 5120 + kvh * 128 + d0 + tx];
  __syncthreads();
#pragma unroll
  for (int i = 0; i < 4; ++i)
    vt[(size_t)((b * NKV + kvh) * HD + d0 + ty + i * 8) * SEQ + s0 + tx] = t[tx][ty + i * 8];
}

// ---------------- Flash attention (causal, GQA), bf16 MFMA ----------------
__global__ __launch_bounds__(256) void attn_kernel(const u16* __restrict__ qkv, const u16* __restrict__ vt,
                                                   u16* __restrict__ attn) {
  __shared__ __align__(16) u16 sQ[64 * 128];
  __shared__ __align__(16) u16 sK[64 * 128];
  __shared__ __align__(16) u16 sV[128 * 64];  // Vt tile: [d][kv]
  __shared__ __align__(16) u16 sP[4][16 * 64];
  const int q0 = (gridDim.x - 1 - blockIdx.x) * 64;  // heavy tiles first
  const int h = blockIdx.y, b = blockIdx.z;
  const int kvh = h >> 2;
  const int tid = threadIdx.x, w = tid >> 6, lane = tid & 63;

  // stage Q tile [64][128] (1024 granules), swizzled source
#pragma unroll
  for (int c = 0; c < 4; ++c) {
    const int g = c * 256 + w * 64 + lane;
    const int r = g >> 4, gc = g & 15;
    gload16(qkv + (size_t)(b * SEQ + q0 + r) * QKV_N + h * 128 + ((gc ^ (r & 7)) << 3),
            &sQ[(c * 256 + w * 64) * 8]);
  }
  __syncthreads();
  // Q fragments to registers (wave w owns q-local rows w*16..w*16+15)
  bf16x8 qf[4];
  {
    const int r = w * 16 + (lane & 15);
#pragma unroll
    for (int ks = 0; ks < 4; ++ks) {
      const int g = (ks * 4 + (lane >> 4)) ^ (r & 7);
      qf[ks] = *(const bf16x8*)&sQ[r * 128 + g * 8];
    }
  }
  float m[4], l[4];
  f32x4 o[8] = {};
#pragma unroll
  for (int j = 0; j < 4; ++j) { m[j] = -1e30f; l[j] = 0.f; }

  for (int k0 = 0; k0 <= q0; k0 += 64) {
    // stage K tile [64][128] and Vt tile [128][64]
#pragma unroll
    for (int c = 0; c < 4; ++c) {
      const int g = c * 256 + w * 64 + lane;
      const int r = g >> 4, gc = g & 15;
      gload16(qkv + (size_t)(b * SEQ + k0 + r) * QKV_N + 4096 + kvh * 128 + ((gc ^ (r & 7)) << 3),
              &sK[(c * 256 + w * 64) * 8]);
    }
#pragma unroll
    for (int c = 0; c < 4; ++c) {
      const int g = c * 256 + w * 64 + lane;
      const int r = g >> 3, gc = g & 7;
      gload16(vt + (size_t)((b * NKV + kvh) * HD + r) * SEQ + k0 + ((gc ^ (r & 7)) << 3),
              &sV[(c * 256 + w * 64) * 8]);
    }
    __syncthreads();
    // S = Q K^T (already scaled to log2 domain via q prescale)
    f32x4 s[4];
#pragma unroll
    for (int ni = 0; ni < 4; ++ni) {
      f32x4 sa = {};
      const int r = ni * 16 + (lane & 15);
#pragma unroll
      for (int ks = 0; ks < 4; ++ks) {
        const int g = (ks * 4 + (lane >> 4)) ^ (r & 7);
        bf16x8 kf = *(const bf16x8*)&sK[r * 128 + g * 8];
        sa = __builtin_amdgcn_mfma_f32_16x16x32_bf16(qf[ks], kf, sa, 0, 0, 0);
      }
      s[ni] = sa;
    }
    if (k0 == q0) {  // diagonal tile: causal mask
#pragma unroll
      for (int ni = 0; ni < 4; ++ni)
#pragma unroll
        for (int j = 0; j < 4; ++j) {
          const int col = k0 + ni * 16 + (lane & 15);
          const int row = q0 + w * 16 + (lane >> 4) * 4 + j;
          if (col > row) s[ni][j] = -1e30f;
        }
    }
    // online softmax (base-2)
    float alpha[4];
#pragma unroll
    for (int j = 0; j < 4; ++j) {
      float mx = fmaxf(fmaxf(s[0][j], s[1][j]), fmaxf(s[2][j], s[3][j]));
      mx = fmaxf(mx, __shfl_xor(mx, 1));
      mx = fmaxf(mx, __shfl_xor(mx, 2));
      mx = fmaxf(mx, __shfl_xor(mx, 4));
      mx = fmaxf(mx, __shfl_xor(mx, 8));
      const float mn = fmaxf(m[j], mx);
      alpha[j] = exp2f(m[j] - mn);
      m[j] = mn;
    }
    float rs[4] = {0.f, 0.f, 0.f, 0.f};
#pragma unroll
    for (int ni = 0; ni < 4; ++ni)
#pragma unroll
      for (int j = 0; j < 4; ++j) {
        const float p = exp2f(s[ni][j] - m[j]);
        rs[j] += p;
        const int rl = (lane >> 4) * 4 + j;
        const int colp = ni * 16 + (lane & 15);
        sP[w][rl * 64 + ((colp >> 3) ^ (rl & 7)) * 8 + (colp & 7)] = f2b(p);
      }
#pragma unroll
    for (int j = 0; j < 4; ++j) {
      rs[j] += __shfl_xor(rs[j], 1);
      rs[j] += __shfl_xor(rs[j], 2);
      rs[j] += __shfl_xor(rs[j], 4);
      rs[j] += __shfl_xor(rs[j], 8);
      l[j] = l[j] * alpha[j] + rs[j];
    }
#pragma unroll
    for (int ni = 0; ni < 8; ++ni)
#pragma unroll
      for (int j = 0; j < 4; ++j) o[ni][j] *= alpha[j];
    asm volatile("s_waitcnt lgkmcnt(0)" ::: "memory");
    // O += P V
#pragma unroll
    for (int ks = 0; ks < 2; ++ks) {
      const int rp = lane & 15;
      const int gp = (ks * 4 + (lane >> 4)) ^ (rp & 7);
      bf16x8 pf = *(const bf16x8*)&sP[w][rp * 64 + gp * 8];
#pragma unroll
      for (int ni = 0; ni < 8; ++ni) {
        const int rv = ni * 16 + (lane & 15);
        const int gv = (ks * 4 + (lane >> 4)) ^ (rv & 7);
        bf16x8 vf = *(const bf16x8*)&sV[rv * 64 + gv * 8];
        o[ni] = __builtin_amdgcn_mfma_f32_16x16x32_bf16(pf, vf, o[ni], 0, 0, 0);
      }
    }
    __syncthreads();
  }
  // epilogue
#pragma unroll
  for (int ni = 0; ni < 8; ++ni)
#pragma unroll
    for (int j = 0; j < 4; ++j) {
      const int row = b * SEQ + q0 + w * 16 + (lane >> 4) * 4 + j;
      const int col = h * 128 + ni * 16 + (lane & 15);
      attn[(size_t)row * 4096 + col] = f2b(o[ni][j] / l[j]);
    }
}

extern "C" void kernel_launch(void* const* d_in, const int* in_sizes, int n_in,
                              void* d_out, int out_size, void* d_ws, size_t ws_size,
                              hipStream_t stream) {
  const float* hs = (const float*)d_in[0];
  const int* pos = (const int*)d_in[1];
  const float* w_qkv = (const float*)d_in[2];
  const float* w_o = (const float*)d_in[3];
  float* out = (float*)d_out;
  char* ws = (char*)d_ws;

  u16* hid = (u16*)ws;                        // 4096*4096 bf16 = 32 MiB
  u16* attnb = hid;                           // reused after qkv GEMM consumes hid
  u16* wT = (u16*)(ws + 33554432);            // up to 6144*4096 bf16 = 48 MiB
  u16* qkv = (u16*)(ws + 83886080);           // 4096*6144 bf16 = 48 MiB
  u16* vt = (u16*)(ws + 134217728);           // 2*8*128*2048 bf16 = 8 MiB

  const float qscale = 0.12751744f;  // (1/sqrt(128)) * log2(e)

  cast_f32_bf16<<<16384, 256, 0, stream>>>(hs, hid, 4096 * 4096);
  cast_transpose<<<dim3(192, 128), dim3(32, 8), 0, stream>>>(w_qkv, wT, 4096, QKV_N);
  gemm_bt<u16><<<1536, 256, 0, stream>>>(hid, wT, qkv, 4096, QKV_N, 4096);
  rope_kernel<<<4096, 256, 0, stream>>>(qkv, pos, qscale);
  v_transpose<<<dim3(64, 4, 16), dim3(32, 8), 0, stream>>>(qkv, vt);
  cast_transpose<<<dim3(128, 128), dim3(32, 8), 0, stream>>>(w_o, wT, 4096, 4096);
  attn_kernel<<<dim3(32, 32, 2), 256, 0, stream>>>(qkv, vt, attnb);
  gemm_bt<float><<<1024, 256, 0, stream>>>(attnb, wT, out, 4096, 4096, 4096);
}

// Round 2
// 608.482 us; speedup vs baseline: 1.3700x; 1.3700x over previous
//
#include <hip/hip_runtime.h>
#include <hip/hip_bf16.h>
#include <stdint.h>
#include <stddef.h>

typedef unsigned short u16;
typedef __bf16 bf16x8 __attribute__((ext_vector_type(8)));
typedef float f32x4 __attribute__((ext_vector_type(4)));
typedef float f32x16 __attribute__((ext_vector_type(16)));
typedef unsigned u32x2 __attribute__((ext_vector_type(2)));

#define NH 32
#define NKV 8
#define HD 128
#define QKV_N 6144
#define SEQ 2048

__device__ __forceinline__ u16 f2b(float x) {
  union { float f; unsigned u; } v; v.f = x;
  unsigned r = v.u + 0x7FFF + ((v.u >> 16) & 1);
  return (u16)(r >> 16);
}
__device__ __forceinline__ float b2f(u16 b) {
  union { float f; unsigned u; } v; v.u = ((unsigned)b) << 16;
  return v.f;
}
__device__ __forceinline__ void gload16(const void* g, void* l) {
  __builtin_amdgcn_global_load_lds((const __attribute__((address_space(1))) unsigned int*)g,
                                   (__attribute__((address_space(3))) unsigned int*)l, 16, 0, 0);
}
__device__ __forceinline__ unsigned pk(float lo, float hi) {
  union { __bf16 h[2]; unsigned w; } u;
  u.h[0] = (__bf16)lo; u.h[1] = (__bf16)hi;
  return u.w;
}
__device__ __forceinline__ void plswap(unsigned& a, unsigned& b) {
  u32x2 r = __builtin_amdgcn_permlane32_swap(a, b, false, false);
  a = r.x; b = r.y;
}
__device__ __forceinline__ float pl_partner_max(float x) {
  unsigned u = __float_as_uint(x);
  u32x2 r = __builtin_amdgcn_permlane32_swap(u, u, false, false);
  return fmaxf(__uint_as_float(r.x), __uint_as_float(r.y));
}
__device__ __forceinline__ float pl_partner_sum(float x) {
  unsigned u = __float_as_uint(x);
  u32x2 r = __builtin_amdgcn_permlane32_swap(u, u, false, false);
  return __uint_as_float(r.x) + __uint_as_float(r.y);
}

// ---------------- cast fp32 -> bf16 (vectorized) ----------------
__global__ void cast_f32_bf16(const float* __restrict__ in, u16* __restrict__ out, int n) {
  int i = (blockIdx.x * blockDim.x + threadIdx.x) * 4;
  if (i >= n) return;
  float4 v = *(const float4*)&in[i];
  ushort4 o;
  o.x = f2b(v.x); o.y = f2b(v.y); o.z = f2b(v.z); o.w = f2b(v.w);
  *(ushort4*)&out[i] = o;
}

// ---------- cast + transpose: in [K][N] fp32 -> out [N][K] bf16 ----------
__global__ void cast_transpose(const float* __restrict__ in, u16* __restrict__ out, int K, int N) {
  __shared__ float t[32][33];
  int n0 = blockIdx.x * 32, k0 = blockIdx.y * 32;
  int tx = threadIdx.x, ty = threadIdx.y;  // (32,8)
#pragma unroll
  for (int i = 0; i < 4; ++i)
    t[ty + i * 8][tx] = in[(size_t)(k0 + ty + i * 8) * N + n0 + tx];
  __syncthreads();
#pragma unroll
  for (int i = 0; i < 4; ++i)
    out[(size_t)(n0 + ty + i * 8) * K + k0 + tx] = f2b(t[tx][ty + i * 8]);
}

// ---------------- GEMM: C[M][N] = A[M][K] * Bt[N][K]^T (bf16 MFMA) ----------------
__device__ __forceinline__ void storeC(float* C, size_t i, float v) { C[i] = v; }
__device__ __forceinline__ void storeC(u16* C, size_t i, float v) { C[i] = f2b(v); }

template <typename OutT>
__global__ __launch_bounds__(256) void gemm_bt(const u16* __restrict__ A, const u16* __restrict__ Bt,
                                               OutT* __restrict__ C, int M, int N, int K) {
  __shared__ __align__(16) u16 sA[128 * 64];
  __shared__ __align__(16) u16 sB[128 * 64];
  const int nbx = N >> 7;
  const int nwg = (M >> 7) * nbx;
  const int cpx = nwg >> 3;
  const int wg = (blockIdx.x & 7) * cpx + (blockIdx.x >> 3);
  const int row0 = (wg / nbx) << 7;
  const int col0 = (wg % nbx) << 7;
  const int tid = threadIdx.x, w = tid >> 6, lane = tid & 63;
  const int wr = (w >> 1) * 64, wc = (w & 1) * 64;
  f32x4 acc[4][4] = {};
  for (int kt = 0; kt < K; kt += 64) {
#pragma unroll
    for (int c = 0; c < 4; ++c) {
      const int g = c * 256 + w * 64 + lane;
      const int r = g >> 3, gc = g & 7;
      const int srcoff = kt + ((gc ^ (r & 7)) << 3);
      gload16(A + (size_t)(row0 + r) * K + srcoff, &sA[(c * 256 + w * 64) * 8]);
      gload16(Bt + (size_t)(col0 + r) * K + srcoff, &sB[(c * 256 + w * 64) * 8]);
    }
    __syncthreads();
#pragma unroll
    for (int ks = 0; ks < 2; ++ks) {
      bf16x8 a[4], b[4];
#pragma unroll
      for (int mi = 0; mi < 4; ++mi) {
        const int r = wr + mi * 16 + (lane & 15);
        const int g = (ks * 4 + (lane >> 4)) ^ (r & 7);
        a[mi] = *(const bf16x8*)&sA[r * 64 + g * 8];
      }
#pragma unroll
      for (int ni = 0; ni < 4; ++ni) {
        const int r = wc + ni * 16 + (lane & 15);
        const int g = (ks * 4 + (lane >> 4)) ^ (r & 7);
        b[ni] = *(const bf16x8*)&sB[r * 64 + g * 8];
      }
#pragma unroll
      for (int mi = 0; mi < 4; ++mi)
#pragma unroll
        for (int ni = 0; ni < 4; ++ni)
          acc[mi][ni] = __builtin_amdgcn_mfma_f32_16x16x32_bf16(a[mi], b[ni], acc[mi][ni], 0, 0, 0);
    }
    __syncthreads();
  }
#pragma unroll
  for (int mi = 0; mi < 4; ++mi)
#pragma unroll
    for (int ni = 0; ni < 4; ++ni)
#pragma unroll
      for (int j = 0; j < 4; ++j) {
        const int row = row0 + wr + mi * 16 + (lane >> 4) * 4 + j;
        const int col = col0 + wc + ni * 16 + (lane & 15);
        storeC(C, (size_t)row * N + col, acc[mi][ni][j]);
      }
}

// ---------------- RoPE (NeoX), in-place on qkv; folds scale*log2e into q ----------------
__global__ void rope_kernel(u16* __restrict__ qkv, const int* __restrict__ pos, float qscale) {
  __shared__ float cs[64], sn[64];
  const int row = blockIdx.x;
  const int tid = threadIdx.x;
  if (tid < 64) {
    float p = (float)pos[row];
    float inv = exp2f(-(float)tid * 0.20762050593046f);
    float a = p * inv;
    cs[tid] = cosf(a);
    sn[tid] = sinf(a);
  }
  __syncthreads();
  const size_t base = (size_t)row * QKV_N;
  for (int i = tid; i < 40 * 64; i += 256) {
    const int h = i >> 6, d = i & 63;
    const size_t o = base + h * 128 + d;
    float x1 = b2f(qkv[o]), x2 = b2f(qkv[o + 64]);
    float c = cs[d], s = sn[d];
    float o1 = x1 * c - x2 * s;
    float o2 = x2 * c + x1 * s;
    if (h < NH) { o1 *= qscale; o2 *= qscale; }
    qkv[o] = f2b(o1);
    qkv[o + 64] = f2b(o2);
  }
}

// ---------------- V transpose: qkv v-section -> vt[(b*8+kvh)*128 + d][2048] ----------------
__global__ void v_transpose(const u16* __restrict__ qkv, u16* __restrict__ vt) {
  __shared__ u16 t[32][33];
  const int b = blockIdx.z >> 3, kvh = blockIdx.z & 7;
  const int s0 = blockIdx.x * 32, d0 = blockIdx.y * 32;
  const int tx = threadIdx.x, ty = threadIdx.y;
#pragma unroll
  for (int i = 0; i < 4; ++i)
    t[ty + i * 8][tx] = qkv[(size_t)(b * SEQ + s0 + ty + i * 8) * QKV_N + 5120 + kvh * 128 + d0 + tx];
  __syncthreads();
#pragma unroll
  for (int i = 0; i < 4; ++i)
    vt[(size_t)((b * NKV + kvh) * HD + d0 + ty + i * 8) * SEQ + s0 + tx] = t[tx][ty + i * 8];
}

// ---------------- Flash attention: 8 waves x 32 q-rows, 32x32x16 MFMA, swapped QK^T ----------------
__global__ __launch_bounds__(512, 2) void attn_kernel(const u16* __restrict__ qkv, const u16* __restrict__ vt,
                                                      u16* __restrict__ attn) {
  __shared__ __align__(16) u16 sK[2][64 * 128];   // [kv][d]
  __shared__ __align__(16) u16 sV[2][128 * 64];   // [d][kv]
  const int b = blockIdx.z, h = blockIdx.y;
  const int qt = (b == 0) ? blockIdx.x : 7 - blockIdx.x;  // anti-correlated pairing for balance
  const int kvh = h >> 2;
  const int qb = qt * 256;
  const int tid = threadIdx.x, w = tid >> 6, lane = tid & 63;
  const int lq = lane & 31, hi = lane >> 5, x7 = lane & 7;
  const int qw = qb + (w << 5);
  const int qa = qw + lq;
  const int nt = 4 * (qt + 1);

  auto stage = [&](int buf, int kt) {
    const int k0 = kt * 64;
#pragma unroll
    for (int c = 0; c < 2; ++c) {
      const int g = c * 512 + tid;
      const int r = g >> 4, gc = g & 15;
      const int gs = gc ^ (r & 7);
      gload16(qkv + (size_t)(b * SEQ + k0 + r) * QKV_N + 4096 + kvh * 128 + gs * 8,
              &sK[buf][(c * 512 + (w << 6)) * 8]);
    }
#pragma unroll
    for (int c = 0; c < 2; ++c) {
      const int g = c * 512 + tid;
      const int r = g >> 3, gc = g & 7;
      const int gs = gc ^ (r & 7);
      gload16(vt + (size_t)((b * NKV + kvh) * HD + r) * SEQ + k0 + gs * 8,
              &sV[buf][(c * 512 + (w << 6)) * 8]);
    }
  };

  stage(0, 0);
  // Q fragments direct from global (B-operand layout: lane holds q-col lq, k = d)
  bf16x8 qf[8];
#pragma unroll
  for (int ks = 0; ks < 8; ++ks)
    qf[ks] = *(const bf16x8*)&qkv[(size_t)(b * SEQ + qw + lq) * QKV_N + h * 128 + ks * 16 + 8 * hi];

  f32x16 o[4] = {};
  float mreg = -1e30f, lreg = 0.f;

  asm volatile("s_waitcnt vmcnt(0)" ::: "memory");
  __builtin_amdgcn_s_barrier();

  for (int kt = 0; kt < nt; ++kt) {
    const int cur = kt & 1;
    const int k0 = kt * 64;
    if (kt + 1 < nt) {
      stage(cur ^ 1, kt + 1);
      asm volatile("s_waitcnt vmcnt(4)" ::: "memory");
    } else {
      asm volatile("s_waitcnt vmcnt(0)" ::: "memory");
    }
    __builtin_amdgcn_s_barrier();

    if (k0 <= qw + 31) {  // wave-active (causal skip)
      const u16* sk = sK[cur];
      // S^T = K * Q  (rows kv, cols q); lane holds q-col lq, kv rows via crow(r,hi)
      f32x16 st0 = {}, st1 = {};
      __builtin_amdgcn_s_setprio(1);
#pragma unroll
      for (int ks = 0; ks < 8; ++ks) {
        const int g = ((2 * ks + hi) ^ x7) * 8;
        bf16x8 kf0 = *(const bf16x8*)&sk[lq * 128 + g];
        bf16x8 kf1 = *(const bf16x8*)&sk[(32 + lq) * 128 + g];
        st0 = __builtin_amdgcn_mfma_f32_32x32x16_bf16(kf0, qf[ks], st0, 0, 0, 0);
        st1 = __builtin_amdgcn_mfma_f32_32x32x16_bf16(kf1, qf[ks], st1, 0, 0, 0);
      }
      __builtin_amdgcn_s_setprio(0);
      // causal mask (only near diagonal)
      if (k0 + 63 > qw) {
#pragma unroll
        for (int r = 0; r < 16; ++r) {
          const int cr = (r & 3) + 8 * (r >> 2) + 4 * hi;
          st0[r] = (k0 + cr <= qa) ? st0[r] : -1e30f;
          st1[r] = (k0 + 32 + cr <= qa) ? st1[r] : -1e30f;
        }
      }
      // tile max (in-lane tree + partner)
      float a8[8];
#pragma unroll
      for (int r = 0; r < 8; ++r)
        a8[r] = fmaxf(fmaxf(st0[r], st0[r + 8]), fmaxf(st1[r], st1[r + 8]));
#pragma unroll
      for (int s = 4; s; s >>= 1)
#pragma unroll
        for (int r = 0; r < s; ++r) a8[r] = fmaxf(a8[r], a8[r + s]);
      const float pm = pl_partner_max(a8[0]);
      // defer-max: rescale only when max grew past threshold
      if (!__all(pm <= mreg + 8.f)) {
        const float mn = fmaxf(mreg, pm);
        const float al = exp2f(mreg - mn);
        lreg *= al;
        mreg = mn;
#pragma unroll
        for (int r = 0; r < 16; ++r) {
          const int cr = (r & 3) + 8 * (r >> 2) + 4 * hi;
          const float ar = __shfl(al, cr, 64);
#pragma unroll
          for (int dn = 0; dn < 4; ++dn) o[dn][r] *= ar;
        }
      }
      // P = exp2(S - m), row-sum
#pragma unroll
      for (int r = 0; r < 16; ++r) {
        st0[r] = exp2f(st0[r] - mreg);
        st1[r] = exp2f(st1[r] - mreg);
      }
      float s8[8];
#pragma unroll
      for (int r = 0; r < 8; ++r)
        s8[r] = (st0[r] + st0[r + 8]) + (st1[r] + st1[r + 8]);
#pragma unroll
      for (int s = 4; s; s >>= 1)
#pragma unroll
        for (int r = 0; r < s; ++r) s8[r] += s8[r + s];
      lreg += pl_partner_sum(s8[0]);
      // P -> A-fragments via pack + permlane32_swap
      union U8 { unsigned w[4]; bf16x8 v; };
      U8 pa[4];
#define PACKFRAG(F, P0, P1, P2, P3, P4, P5, P6, P7)                   \
      {                                                               \
        unsigned a0 = pk(P0, P1), a1 = pk(P2, P3);                    \
        unsigned b0 = pk(P4, P5), b1 = pk(P6, P7);                    \
        plswap(a0, b0); plswap(a1, b1);                               \
        pa[F].w[0] = a0; pa[F].w[1] = a1; pa[F].w[2] = b0; pa[F].w[3] = b1; \
      }
      PACKFRAG(0, st0[0], st0[1], st0[2], st0[3], st0[4], st0[5], st0[6], st0[7])
      PACKFRAG(1, st0[8], st0[9], st0[10], st0[11], st0[12], st0[13], st0[14], st0[15])
      PACKFRAG(2, st1[0], st1[1], st1[2], st1[3], st1[4], st1[5], st1[6], st1[7])
      PACKFRAG(3, st1[8], st1[9], st1[10], st1[11], st1[12], st1[13], st1[14], st1[15])
#undef PACKFRAG
      // O += P V   (A = P frags, B = V^T cols)
      const u16* sv = sV[cur];
      __builtin_amdgcn_s_setprio(1);
#pragma unroll
      for (int dn = 0; dn < 4; ++dn) {
#pragma unroll
        for (int ks = 0; ks < 4; ++ks) {
          bf16x8 vf = *(const bf16x8*)&sv[(dn * 32 + lq) * 64 + (((2 * ks + hi) ^ x7)) * 8];
          o[dn] = __builtin_amdgcn_mfma_f32_32x32x16_bf16(pa[ks].v, vf, o[dn], 0, 0, 0);
        }
      }
      __builtin_amdgcn_s_setprio(0);
    }
    __builtin_amdgcn_s_barrier();
  }

  // epilogue: normalize rows and store
  const float inv = 1.0f / lreg;
#pragma unroll
  for (int r = 0; r < 16; ++r) {
    const int cr = (r & 3) + 8 * (r >> 2) + 4 * hi;
    const float fr = __shfl(inv, cr, 64);
    const size_t row = (size_t)(b * SEQ + qw + cr);
#pragma unroll
    for (int dn = 0; dn < 4; ++dn)
      attn[row * 4096 + h * 128 + dn * 32 + lq] = f2b(o[dn][r] * fr);
  }
}

extern "C" void kernel_launch(void* const* d_in, const int* in_sizes, int n_in,
                              void* d_out, int out_size, void* d_ws, size_t ws_size,
                              hipStream_t stream) {
  const float* hs = (const float*)d_in[0];
  const int* pos = (const int*)d_in[1];
  const float* w_qkv = (const float*)d_in[2];
  const float* w_o = (const float*)d_in[3];
  float* out = (float*)d_out;
  char* ws = (char*)d_ws;

  u16* hid = (u16*)ws;                        // 4096*4096 bf16 = 32 MiB
  u16* attnb = hid;                           // reused after qkv GEMM consumes hid
  u16* wT = (u16*)(ws + 33554432);            // up to 6144*4096 bf16 = 48 MiB
  u16* qkv = (u16*)(ws + 83886080);           // 4096*6144 bf16 = 48 MiB
  u16* vt = (u16*)(ws + 134217728);           // 2*8*128*2048 bf16 = 8 MiB

  const float qscale = 0.12751744f;  // (1/sqrt(128)) * log2(e)

  cast_f32_bf16<<<16384, 256, 0, stream>>>(hs, hid, 4096 * 4096);
  cast_transpose<<<dim3(192, 128), dim3(32, 8), 0, stream>>>(w_qkv, wT, 4096, QKV_N);
  gemm_bt<u16><<<1536, 256, 0, stream>>>(hid, wT, qkv, 4096, QKV_N, 4096);
  rope_kernel<<<4096, 256, 0, stream>>>(qkv, pos, qscale);
  v_transpose<<<dim3(64, 4, 16), dim3(32, 8), 0, stream>>>(qkv, vt);
  cast_transpose<<<dim3(128, 128), dim3(32, 8), 0, stream>>>(w_o, wT, 4096, 4096);
  attn_kernel<<<dim3(8, 32, 2), 512, 0, stream>>>(qkv, vt, attnb);
  gemm_bt<float><<<1024, 256, 0, stream>>>(attnb, wT, out, 4096, 4096, 4096);
}

// Round 3
// 589.450 us; speedup vs baseline: 1.4143x; 1.0323x over previous
//
#include <hip/hip_runtime.h>
#include <hip/hip_bf16.h>
#include <stdint.h>
#include <stddef.h>

typedef unsigned short u16;
typedef __bf16 bf16x8 __attribute__((ext_vector_type(8)));
typedef float f32x4 __attribute__((ext_vector_type(4)));
typedef float f32x16 __attribute__((ext_vector_type(16)));
typedef unsigned u32x2 __attribute__((ext_vector_type(2)));

#define NH 32
#define NKV 8
#define HD 128
#define QKV_N 6144
#define SEQ 2048

__device__ __forceinline__ u16 f2b(float x) {
  union { float f; unsigned u; } v; v.f = x;
  unsigned r = v.u + 0x7FFF + ((v.u >> 16) & 1);
  return (u16)(r >> 16);
}
__device__ __forceinline__ float b2f(u16 b) {
  union { float f; unsigned u; } v; v.u = ((unsigned)b) << 16;
  return v.f;
}
__device__ __forceinline__ void gload16(const void* g, void* l) {
  __builtin_amdgcn_global_load_lds((const __attribute__((address_space(1))) unsigned int*)g,
                                   (__attribute__((address_space(3))) unsigned int*)l, 16, 0, 0);
}
__device__ __forceinline__ unsigned pk(float lo, float hi) {
  union { __bf16 h[2]; unsigned w; } u;
  u.h[0] = (__bf16)lo; u.h[1] = (__bf16)hi;
  return u.w;
}
__device__ __forceinline__ void plswap(unsigned& a, unsigned& b) {
  u32x2 r = __builtin_amdgcn_permlane32_swap(a, b, false, false);
  a = r.x; b = r.y;
}
__device__ __forceinline__ float pl_partner_max(float x) {
  unsigned u = __float_as_uint(x);
  u32x2 r = __builtin_amdgcn_permlane32_swap(u, u, false, false);
  return fmaxf(__uint_as_float(r.x), __uint_as_float(r.y));
}
__device__ __forceinline__ float pl_partner_sum(float x) {
  unsigned u = __float_as_uint(x);
  u32x2 r = __builtin_amdgcn_permlane32_swap(u, u, false, false);
  return __uint_as_float(r.x) + __uint_as_float(r.y);
}

// ---------------- cast fp32 -> bf16 (vectorized) ----------------
__global__ void cast_f32_bf16(const float* __restrict__ in, u16* __restrict__ out, int n) {
  int i = (blockIdx.x * blockDim.x + threadIdx.x) * 4;
  if (i >= n) return;
  float4 v = *(const float4*)&in[i];
  ushort4 o;
  o.x = f2b(v.x); o.y = f2b(v.y); o.z = f2b(v.z); o.w = f2b(v.w);
  *(ushort4*)&out[i] = o;
}

// ---------- cast + transpose: in [K][N] fp32 -> out [N][K] bf16 ----------
__global__ void cast_transpose(const float* __restrict__ in, u16* __restrict__ out, int K, int N) {
  __shared__ float t[32][33];
  int n0 = blockIdx.x * 32, k0 = blockIdx.y * 32;
  int tx = threadIdx.x, ty = threadIdx.y;  // (32,8)
#pragma unroll
  for (int i = 0; i < 4; ++i)
    t[ty + i * 8][tx] = in[(size_t)(k0 + ty + i * 8) * N + n0 + tx];
  __syncthreads();
#pragma unroll
  for (int i = 0; i < 4; ++i)
    out[(size_t)(n0 + ty + i * 8) * K + k0 + tx] = f2b(t[tx][ty + i * 8]);
}

__device__ __forceinline__ void storeC(float* C, size_t i, float v) { C[i] = v; }
__device__ __forceinline__ void storeC(u16* C, size_t i, float v) { C[i] = f2b(v); }

// ------------- 256x256 8-phase GEMM: C[M][N] = A[M][K] * Bt[N][K]^T -------------
// 8 waves (2M x 4N), BK=64, 2-deep LDS double buffer (128 KiB), counted vmcnt.
// Phase q computes C-quadrant (ah=q>>1, bh=q&1); operand-half consumption order
// A-lo(last read q1), B-lo(q2), A-hi/B-hi(q3) lets stages q2/q3 overwrite cur-buf
// lo-halves for tile t+2 while hi-halves are being read.
template <typename OutT>
__global__ __launch_bounds__(512, 2) void gemm256(const u16* __restrict__ A, const u16* __restrict__ Bt,
                                                  OutT* __restrict__ C, int M, int N, int K) {
  __shared__ __align__(16) u16 sA[2 * 256 * 64];
  __shared__ __align__(16) u16 sB[2 * 256 * 64];
  const int nbx = N >> 8;
  const int nwg = (M >> 8) * nbx;
  const int cpx = nwg >> 3;  // nwg % 8 == 0 for our shapes
  const int wg = ((int)blockIdx.x & 7) * cpx + ((int)blockIdx.x >> 3);
  const int row0 = (wg / nbx) << 8, col0 = (wg % nbx) << 8;
  const int tid = threadIdx.x, w = tid >> 6, lane = tid & 63;
  const int wm = w >> 2, wn = w & 3;
  const int lq = lane & 15, lh = lane >> 4, x7 = lq & 7;
  const int o0 = (lh ^ x7) << 3, o1 = ((4 + lh) ^ x7) << 3;  // swizzled ks=0/1 granule offsets (u16)
  const int sr7 = (tid >> 3) & 7;                              // stage-side r&7
  const int nt = K >> 6;

  auto stage = [&](const u16* __restrict__ src, u16* lbase, int rblk, int half, int t) {
#pragma unroll
    for (int c = 0; c < 2; ++c) {
      const int g = c * 512 + tid;
      const int r = g >> 3, gc = g & 7;
      gload16(src + (size_t)(rblk + half * 128 + r) * K + t * 64 + ((gc ^ sr7) << 3),
              lbase + (half * 1024 + c * 512 + (w << 6)) * 8);
    }
  };

  f32x4 acc[4][4][2] = {};

  // prologue: A-lo0, B-lo0, B-hi0, A-hi0, A-lo1, B-lo1  (12 loads/thread)
  stage(A, sA, row0, 0, 0);
  stage(Bt, sB, col0, 0, 0);
  stage(Bt, sB, col0, 1, 0);
  stage(A, sA, row0, 1, 0);
  stage(A, sA + 16384, row0, 0, 1);
  stage(Bt, sB + 16384, col0, 0, 1);
  asm volatile("s_waitcnt vmcnt(6)" ::: "memory");  // A-lo0,B-lo0,B-hi0 landed
  __builtin_amdgcn_s_barrier();

  for (int t = 0; t < nt; ++t) {
    const int cur = t & 1;
    u16* curA = sA + cur * 16384;
    u16* curB = sB + cur * 16384;
    u16* nxtA = sA + (cur ^ 1) * 16384;
    u16* nxtB = sB + (cur ^ 1) * 16384;
#pragma unroll
    for (int q = 0; q < 4; ++q) {
      const int ah = q >> 1, bh = q & 1;
      bf16x8 af[4][2], bfr[2][2];
      const u16* pa = curA + (ah * 128 + wm * 64 + lq) * 64;
      const u16* pb = curB + (bh * 128 + wn * 32 + lq) * 64;
#pragma unroll
      for (int mi = 0; mi < 4; ++mi) {
        af[mi][0] = *(const bf16x8*)&pa[mi * 1024 + o0];
        af[mi][1] = *(const bf16x8*)&pa[mi * 1024 + o1];
      }
#pragma unroll
      for (int ni = 0; ni < 2; ++ni) {
        bfr[ni][0] = *(const bf16x8*)&pb[ni * 1024 + o0];
        bfr[ni][1] = *(const bf16x8*)&pb[ni * 1024 + o1];
      }
      // stage rotation: q0->B-hi(t+1), q1->A-hi(t+1), q2->A-lo(t+2), q3->B-lo(t+2)
      if (q == 0 && t + 1 < nt) stage(Bt, nxtB, col0, 1, t + 1);
      if (q == 1 && t + 1 < nt) stage(A, nxtA, row0, 1, t + 1);
      if (q == 2 && t + 2 < nt) stage(A, curA, row0, 0, t + 2);
      if (q == 3 && t + 2 < nt) stage(Bt, curB, col0, 0, t + 2);
      __builtin_amdgcn_s_barrier();
      __builtin_amdgcn_s_setprio(1);
#pragma unroll
      for (int ks = 0; ks < 2; ++ks)
#pragma unroll
        for (int mi = 0; mi < 4; ++mi)
#pragma unroll
          for (int ni = 0; ni < 2; ++ni)
            acc[q][mi][ni] = __builtin_amdgcn_mfma_f32_16x16x32_bf16(af[mi][ks], bfr[ni][ks], acc[q][mi][ni], 0, 0, 0);
      __builtin_amdgcn_s_setprio(0);
      // counted vmcnt BEFORE a barrier so the guarantee is cross-wave
      if (q == 1) {
        if (t < nt - 1) asm volatile("s_waitcnt vmcnt(8)" ::: "memory");  // A-hi(t) landed
        else            asm volatile("s_waitcnt vmcnt(0)" ::: "memory");  // final drain
      }
      if (q == 3 && t < nt - 1) {
        if (t + 1 < nt - 1) asm volatile("s_waitcnt vmcnt(6)" ::: "memory");  // lo/B-hi(t+1) landed
        else                asm volatile("s_waitcnt vmcnt(2)" ::: "memory");  // tail
      }
      __builtin_amdgcn_s_barrier();
    }
  }

#pragma unroll
  for (int q = 0; q < 4; ++q) {
    const int ah = q >> 1, bh = q & 1;
#pragma unroll
    for (int mi = 0; mi < 4; ++mi)
#pragma unroll
      for (int ni = 0; ni < 2; ++ni)
#pragma unroll
        for (int j = 0; j < 4; ++j) {
          const int row = row0 + ah * 128 + wm * 64 + mi * 16 + lh * 4 + j;
          const int col = col0 + bh * 128 + wn * 32 + ni * 16 + lq;
          storeC(C, (size_t)row * N + col, acc[q][mi][ni][j]);
        }
  }
}

// ---------------- RoPE (NeoX), in-place on qkv; folds scale*log2e into q ----------------
__global__ void rope_kernel(u16* __restrict__ qkv, const int* __restrict__ pos, float qscale) {
  __shared__ float cs[64], sn[64];
  const int row = blockIdx.x;
  const int tid = threadIdx.x;
  if (tid < 64) {
    float p = (float)pos[row];
    float inv = exp2f(-(float)tid * 0.20762050593046f);
    float a = p * inv;
    cs[tid] = cosf(a);
    sn[tid] = sinf(a);
  }
  __syncthreads();
  const size_t base = (size_t)row * QKV_N;
  for (int i = tid; i < 40 * 64; i += 256) {
    const int h = i >> 6, d = i & 63;
    const size_t o = base + h * 128 + d;
    float x1 = b2f(qkv[o]), x2 = b2f(qkv[o + 64]);
    float c = cs[d], s = sn[d];
    float o1 = x1 * c - x2 * s;
    float o2 = x2 * c + x1 * s;
    if (h < NH) { o1 *= qscale; o2 *= qscale; }
    qkv[o] = f2b(o1);
    qkv[o + 64] = f2b(o2);
  }
}

// ---------------- V transpose: qkv v-section -> vt[(b*8+kvh)*128 + d][2048] ----------------
__global__ void v_transpose(const u16* __restrict__ qkv, u16* __restrict__ vt) {
  __shared__ u16 t[32][33];
  const int b = blockIdx.z >> 3, kvh = blockIdx.z & 7;
  const int s0 = blockIdx.x * 32, d0 = blockIdx.y * 32;
  const int tx = threadIdx.x, ty = threadIdx.y;
#pragma unroll
  for (int i = 0; i < 4; ++i)
    t[ty + i * 8][tx] = qkv[(size_t)(b * SEQ + s0 + ty + i * 8) * QKV_N + 5120 + kvh * 128 + d0 + tx];
  __syncthreads();
#pragma unroll
  for (int i = 0; i < 4; ++i)
    vt[(size_t)((b * NKV + kvh) * HD + d0 + ty + i * 8) * SEQ + s0 + tx] = t[tx][ty + i * 8];
}

// ---------------- Flash attention: 8 waves x 32 q-rows, 32x32x16 MFMA, swapped QK^T ----------------
__global__ __launch_bounds__(512, 2) void attn_kernel(const u16* __restrict__ qkv, const u16* __restrict__ vt,
                                                      u16* __restrict__ attn) {
  __shared__ __align__(16) u16 sK[2][64 * 128];   // [kv][d]
  __shared__ __align__(16) u16 sV[2][128 * 64];   // [d][kv]
  const int b = blockIdx.z, h = blockIdx.y;
  const int qt = (b == 0) ? blockIdx.x : 7 - blockIdx.x;  // anti-correlated pairing for balance
  const int kvh = h >> 2;
  const int qb = qt * 256;
  const int tid = threadIdx.x, w = tid >> 6, lane = tid & 63;
  const int lq = lane & 31, hi = lane >> 5, x7 = lane & 7;
  const int qw = qb + (w << 5);
  const int qa = qw + lq;
  const int nt = 4 * (qt + 1);

  auto stage = [&](int buf, int kt) {
    const int k0 = kt * 64;
#pragma unroll
    for (int c = 0; c < 2; ++c) {
      const int g = c * 512 + tid;
      const int r = g >> 4, gc = g & 15;
      const int gs = gc ^ (r & 7);
      gload16(qkv + (size_t)(b * SEQ + k0 + r) * QKV_N + 4096 + kvh * 128 + gs * 8,
              &sK[buf][(c * 512 + (w << 6)) * 8]);
    }
#pragma unroll
    for (int c = 0; c < 2; ++c) {
      const int g = c * 512 + tid;
      const int r = g >> 3, gc = g & 7;
      const int gs = gc ^ (r & 7);
      gload16(vt + (size_t)((b * NKV + kvh) * HD + r) * SEQ + k0 + gs * 8,
              &sV[buf][(c * 512 + (w << 6)) * 8]);
    }
  };

  stage(0, 0);
  bf16x8 qf[8];
#pragma unroll
  for (int ks = 0; ks < 8; ++ks)
    qf[ks] = *(const bf16x8*)&qkv[(size_t)(b * SEQ + qw + lq) * QKV_N + h * 128 + ks * 16 + 8 * hi];

  f32x16 o[4] = {};
  float mreg = -1e30f, lreg = 0.f;

  asm volatile("s_waitcnt vmcnt(0)" ::: "memory");
  __builtin_amdgcn_s_barrier();

  for (int kt = 0; kt < nt; ++kt) {
    const int cur = kt & 1;
    const int k0 = kt * 64;
    if (kt + 1 < nt) {
      stage(cur ^ 1, kt + 1);
      asm volatile("s_waitcnt vmcnt(4)" ::: "memory");
    } else {
      asm volatile("s_waitcnt vmcnt(0)" ::: "memory");
    }
    __builtin_amdgcn_s_barrier();

    if (k0 <= qw + 31) {  // wave-active (causal skip)
      const u16* sk = sK[cur];
      f32x16 st0 = {}, st1 = {};
      __builtin_amdgcn_s_setprio(1);
#pragma unroll
      for (int ks = 0; ks < 8; ++ks) {
        const int g = ((2 * ks + hi) ^ x7) * 8;
        bf16x8 kf0 = *(const bf16x8*)&sk[lq * 128 + g];
        bf16x8 kf1 = *(const bf16x8*)&sk[(32 + lq) * 128 + g];
        st0 = __builtin_amdgcn_mfma_f32_32x32x16_bf16(kf0, qf[ks], st0, 0, 0, 0);
        st1 = __builtin_amdgcn_mfma_f32_32x32x16_bf16(kf1, qf[ks], st1, 0, 0, 0);
      }
      __builtin_amdgcn_s_setprio(0);
      if (k0 + 63 > qw) {
#pragma unroll
        for (int r = 0; r < 16; ++r) {
          const int cr = (r & 3) + 8 * (r >> 2) + 4 * hi;
          st0[r] = (k0 + cr <= qa) ? st0[r] : -1e30f;
          st1[r] = (k0 + 32 + cr <= qa) ? st1[r] : -1e30f;
        }
      }
      float a8[8];
#pragma unroll
      for (int r = 0; r < 8; ++r)
        a8[r] = fmaxf(fmaxf(st0[r], st0[r + 8]), fmaxf(st1[r], st1[r + 8]));
#pragma unroll
      for (int s = 4; s; s >>= 1)
#pragma unroll
        for (int r = 0; r < s; ++r) a8[r] = fmaxf(a8[r], a8[r + s]);
      const float pm = pl_partner_max(a8[0]);
      if (!__all(pm <= mreg + 8.f)) {
        const float mn = fmaxf(mreg, pm);
        const float al = exp2f(mreg - mn);
        lreg *= al;
        mreg = mn;
#pragma unroll
        for (int r = 0; r < 16; ++r) {
          const int cr = (r & 3) + 8 * (r >> 2) + 4 * hi;
          const float ar = __shfl(al, cr, 64);
#pragma unroll
          for (int dn = 0; dn < 4; ++dn) o[dn][r] *= ar;
        }
      }
#pragma unroll
      for (int r = 0; r < 16; ++r) {
        st0[r] = exp2f(st0[r] - mreg);
        st1[r] = exp2f(st1[r] - mreg);
      }
      float s8[8];
#pragma unroll
      for (int r = 0; r < 8; ++r)
        s8[r] = (st0[r] + st0[r + 8]) + (st1[r] + st1[r + 8]);
#pragma unroll
      for (int s = 4; s; s >>= 1)
#pragma unroll
        for (int r = 0; r < s; ++r) s8[r] += s8[r + s];
      lreg += pl_partner_sum(s8[0]);
      union U8 { unsigned w[4]; bf16x8 v; };
      U8 pa[4];
#define PACKFRAG(F, P0, P1, P2, P3, P4, P5, P6, P7)                   \
      {                                                               \
        unsigned a0 = pk(P0, P1), a1 = pk(P2, P3);                    \
        unsigned b0 = pk(P4, P5), b1 = pk(P6, P7);                    \
        plswap(a0, b0); plswap(a1, b1);                               \
        pa[F].w[0] = a0; pa[F].w[1] = a1; pa[F].w[2] = b0; pa[F].w[3] = b1; \
      }
      PACKFRAG(0, st0[0], st0[1], st0[2], st0[3], st0[4], st0[5], st0[6], st0[7])
      PACKFRAG(1, st0[8], st0[9], st0[10], st0[11], st0[12], st0[13], st0[14], st0[15])
      PACKFRAG(2, st1[0], st1[1], st1[2], st1[3], st1[4], st1[5], st1[6], st1[7])
      PACKFRAG(3, st1[8], st1[9], st1[10], st1[11], st1[12], st1[13], st1[14], st1[15])
#undef PACKFRAG
      const u16* sv = sV[cur];
      __builtin_amdgcn_s_setprio(1);
#pragma unroll
      for (int dn = 0; dn < 4; ++dn) {
#pragma unroll
        for (int ks = 0; ks < 4; ++ks) {
          bf16x8 vf = *(const bf16x8*)&sv[(dn * 32 + lq) * 64 + (((2 * ks + hi) ^ x7)) * 8];
          o[dn] = __builtin_amdgcn_mfma_f32_32x32x16_bf16(pa[ks].v, vf, o[dn], 0, 0, 0);
        }
      }
      __builtin_amdgcn_s_setprio(0);
    }
    __builtin_amdgcn_s_barrier();
  }

  const float inv = 1.0f / lreg;
#pragma unroll
  for (int r = 0; r < 16; ++r) {
    const int cr = (r & 3) + 8 * (r >> 2) + 4 * hi;
    const float fr = __shfl(inv, cr, 64);
    const size_t row = (size_t)(b * SEQ + qw + cr);
#pragma unroll
    for (int dn = 0; dn < 4; ++dn)
      attn[row * 4096 + h * 128 + dn * 32 + lq] = f2b(o[dn][r] * fr);
  }
}

extern "C" void kernel_launch(void* const* d_in, const int* in_sizes, int n_in,
                              void* d_out, int out_size, void* d_ws, size_t ws_size,
                              hipStream_t stream) {
  const float* hs = (const float*)d_in[0];
  const int* pos = (const int*)d_in[1];
  const float* w_qkv = (const float*)d_in[2];
  const float* w_o = (const float*)d_in[3];
  float* out = (float*)d_out;
  char* ws = (char*)d_ws;

  u16* hid = (u16*)ws;                        // 4096*4096 bf16 = 32 MiB
  u16* attnb = hid;                           // reused after qkv GEMM consumes hid
  u16* wT = (u16*)(ws + 33554432);            // up to 6144*4096 bf16 = 48 MiB
  u16* qkv = (u16*)(ws + 83886080);           // 4096*6144 bf16 = 48 MiB
  u16* vt = (u16*)(ws + 134217728);           // 2*8*128*2048 bf16 = 8 MiB

  const float qscale = 0.12751744f;  // (1/sqrt(128)) * log2(e)

  cast_f32_bf16<<<16384, 256, 0, stream>>>(hs, hid, 4096 * 4096);
  cast_transpose<<<dim3(192, 128), dim3(32, 8), 0, stream>>>(w_qkv, wT, 4096, QKV_N);
  gemm256<u16><<<384, 512, 0, stream>>>(hid, wT, qkv, 4096, QKV_N, 4096);
  rope_kernel<<<4096, 256, 0, stream>>>(qkv, pos, qscale);
  v_transpose<<<dim3(64, 4, 16), dim3(32, 8), 0, stream>>>(qkv, vt);
  cast_transpose<<<dim3(128, 128), dim3(32, 8), 0, stream>>>(w_o, wT, 4096, 4096);
  attn_kernel<<<dim3(8, 32, 2), 512, 0, stream>>>(qkv, vt, attnb);
  gemm256<float><<<256, 512, 0, stream>>>(attnb, wT, out, 4096, 4096, 4096);
}

// Round 4
// 538.932 us; speedup vs baseline: 1.5469x; 1.0937x over previous
//
#include <hip/hip_runtime.h>
#include <hip/hip_bf16.h>
#include <stdint.h>
#include <stddef.h>

typedef unsigned short u16;
typedef __bf16 bf16x8 __attribute__((ext_vector_type(8)));
typedef float f32x4 __attribute__((ext_vector_type(4)));
typedef float f32x16 __attribute__((ext_vector_type(16)));
typedef unsigned u32x2 __attribute__((ext_vector_type(2)));

#define NH 32
#define NKV 8
#define HD 128
#define QKV_N 6144
#define SEQ 2048

__device__ __forceinline__ u16 f2b(float x) {
  union { float f; unsigned u; } v; v.f = x;
  unsigned r = v.u + 0x7FFF + ((v.u >> 16) & 1);
  return (u16)(r >> 16);
}
__device__ __forceinline__ float b2f(u16 b) {
  union { float f; unsigned u; } v; v.u = ((unsigned)b) << 16;
  return v.f;
}
__device__ __forceinline__ void gload16(const void* g, void* l) {
  __builtin_amdgcn_global_load_lds((const __attribute__((address_space(1))) unsigned int*)g,
                                   (__attribute__((address_space(3))) unsigned int*)l, 16, 0, 0);
}
__device__ __forceinline__ unsigned pk(float lo, float hi) {
  union { __bf16 h[2]; unsigned w; } u;
  u.h[0] = (__bf16)lo; u.h[1] = (__bf16)hi;
  return u.w;
}
__device__ __forceinline__ void plswap(unsigned& a, unsigned& b) {
  u32x2 r = __builtin_amdgcn_permlane32_swap(a, b, false, false);
  a = r.x; b = r.y;
}
__device__ __forceinline__ float pl_partner_max(float x) {
  unsigned u = __float_as_uint(x);
  u32x2 r = __builtin_amdgcn_permlane32_swap(u, u, false, false);
  return fmaxf(__uint_as_float(r.x), __uint_as_float(r.y));
}
__device__ __forceinline__ float pl_partner_sum(float x) {
  unsigned u = __float_as_uint(x);
  u32x2 r = __builtin_amdgcn_permlane32_swap(u, u, false, false);
  return __uint_as_float(r.x) + __uint_as_float(r.y);
}

// ---------------- cast fp32 -> bf16 (vectorized) ----------------
__global__ void cast_f32_bf16(const float* __restrict__ in, u16* __restrict__ out, int n) {
  int i = (blockIdx.x * blockDim.x + threadIdx.x) * 4;
  if (i >= n) return;
  float4 v = *(const float4*)&in[i];
  ushort4 o;
  o.x = f2b(v.x); o.y = f2b(v.y); o.z = f2b(v.z); o.w = f2b(v.w);
  *(ushort4*)&out[i] = o;
}

// ---------- cast + transpose: in [K][N] fp32 -> out [N][K] bf16 ----------
__global__ void cast_transpose(const float* __restrict__ in, u16* __restrict__ out, int K, int N) {
  __shared__ float t[32][33];
  int n0 = blockIdx.x * 32, k0 = blockIdx.y * 32;
  int tx = threadIdx.x, ty = threadIdx.y;  // (32,8)
#pragma unroll
  for (int i = 0; i < 4; ++i)
    t[ty + i * 8][tx] = in[(size_t)(k0 + ty + i * 8) * N + n0 + tx];
  __syncthreads();
#pragma unroll
  for (int i = 0; i < 4; ++i)
    out[(size_t)(n0 + ty + i * 8) * K + k0 + tx] = f2b(t[tx][ty + i * 8]);
}

__device__ __forceinline__ void storeC(float* C, size_t i, float v) { C[i] = v; }
__device__ __forceinline__ void storeC(u16* C, size_t i, float v) { C[i] = f2b(v); }

// ------------- 256x256 2-phase GEMM: C[M][N] = A[M][K] * Bt[N][K]^T -------------
// 8 waves (2M x 4N), BK=64, 2-deep LDS double buffer (128 KiB).
// P0: read A-lo frags + BOTH B-half frags (held in regs); MFMA A-lo x {B-lo,B-hi}.
// P1: read A-hi frags only; MFMA A-hi x {B-lo,B-hi}.
// 24 ds_read_b128 per tile per wave (vs 48 in the quadrant scheme).
// Stage rotation: P0 -> B-hi(t+1), A-hi(t+1); P1 -> A-lo(t+2), B-lo(t+2).
// Steady-state vmem queue entering tile t: [A-hi(t), A-lo(t+1), B-lo(t+1)] (6).
template <typename OutT>
__global__ __launch_bounds__(512, 2) void gemm256(const u16* __restrict__ A, const u16* __restrict__ Bt,
                                                  OutT* __restrict__ C, int M, int N, int K) {
  __shared__ __align__(16) u16 sA[2 * 256 * 64];
  __shared__ __align__(16) u16 sB[2 * 256 * 64];
  const int nbx = N >> 8;
  const int nwg = (M >> 8) * nbx;
  const int cpx = nwg >> 3;  // nwg % 8 == 0 for our shapes
  const int wg = ((int)blockIdx.x & 7) * cpx + ((int)blockIdx.x >> 3);
  const int row0 = (wg / nbx) << 8, col0 = (wg % nbx) << 8;
  const int tid = threadIdx.x, w = tid >> 6, lane = tid & 63;
  const int wm = w >> 2, wn = w & 3;
  const int lq = lane & 15, lh = lane >> 4, x7 = lq & 7;
  const int o0 = (lh ^ x7) << 3, o1 = ((4 + lh) ^ x7) << 3;  // swizzled ks=0/1 granule offsets (u16)
  const int sr7 = (tid >> 3) & 7;                              // stage-side r&7
  const int nt = K >> 6;

  auto stage = [&](const u16* __restrict__ src, u16* lbase, int rblk, int half, int t) {
#pragma unroll
    for (int c = 0; c < 2; ++c) {
      const int g = c * 512 + tid;
      const int r = g >> 3, gc = g & 7;
      gload16(src + (size_t)(rblk + half * 128 + r) * K + t * 64 + ((gc ^ sr7) << 3),
              lbase + (half * 1024 + c * 512 + (w << 6)) * 8);
    }
  };

  f32x4 acc[4][4][2] = {};

  // prologue: A-lo0, B-lo0, B-hi0, A-hi0, A-lo1, B-lo1  (12 loads/thread)
  stage(A, sA, row0, 0, 0);
  stage(Bt, sB, col0, 0, 0);
  stage(Bt, sB, col0, 1, 0);
  stage(A, sA, row0, 1, 0);
  stage(A, sA + 16384, row0, 0, 1);
  stage(Bt, sB + 16384, col0, 0, 1);
  asm volatile("s_waitcnt vmcnt(6)" ::: "memory");  // A-lo0,B-lo0,B-hi0 landed
  __builtin_amdgcn_s_barrier();

  for (int t = 0; t < nt; ++t) {
    const int cur = t & 1;
    u16* curA = sA + cur * 16384;
    u16* curB = sB + cur * 16384;
    u16* nxtA = sA + (cur ^ 1) * 16384;
    u16* nxtB = sB + (cur ^ 1) * 16384;

    // ---------- P0: A-lo frags + both B-half frags ----------
    bf16x8 af[4][2], bfr[2][2][2];
    {
      const u16* pa = curA + (wm * 64 + lq) * 64;
#pragma unroll
      for (int mi = 0; mi < 4; ++mi) {
        af[mi][0] = *(const bf16x8*)&pa[mi * 1024 + o0];
        af[mi][1] = *(const bf16x8*)&pa[mi * 1024 + o1];
      }
#pragma unroll
      for (int bh = 0; bh < 2; ++bh) {
        const u16* pb = curB + (bh * 128 + wn * 32 + lq) * 64;
#pragma unroll
        for (int ni = 0; ni < 2; ++ni) {
          bfr[bh][ni][0] = *(const bf16x8*)&pb[ni * 1024 + o0];
          bfr[bh][ni][1] = *(const bf16x8*)&pb[ni * 1024 + o1];
        }
      }
    }
    if (t + 1 < nt) {
      stage(Bt, nxtB, col0, 1, t + 1);
      stage(A, nxtA, row0, 1, t + 1);
    }
    __builtin_amdgcn_s_barrier();
    __builtin_amdgcn_s_setprio(1);
#pragma unroll
    for (int ks = 0; ks < 2; ++ks)
#pragma unroll
      for (int mi = 0; mi < 4; ++mi)
#pragma unroll
        for (int ni = 0; ni < 2; ++ni) {
          acc[0][mi][ni] = __builtin_amdgcn_mfma_f32_16x16x32_bf16(af[mi][ks], bfr[0][ni][ks], acc[0][mi][ni], 0, 0, 0);
          acc[1][mi][ni] = __builtin_amdgcn_mfma_f32_16x16x32_bf16(af[mi][ks], bfr[1][ni][ks], acc[1][mi][ni], 0, 0, 0);
        }
    __builtin_amdgcn_s_setprio(0);
    if (t < nt - 1) asm volatile("s_waitcnt vmcnt(8)" ::: "memory");  // A-hi(t) landed
    else            asm volatile("s_waitcnt vmcnt(0)" ::: "memory");
    __builtin_amdgcn_s_barrier();

    // ---------- P1: A-hi frags (B held in regs) ----------
    {
      const u16* pa = curA + (128 + wm * 64 + lq) * 64;
#pragma unroll
      for (int mi = 0; mi < 4; ++mi) {
        af[mi][0] = *(const bf16x8*)&pa[mi * 1024 + o0];
        af[mi][1] = *(const bf16x8*)&pa[mi * 1024 + o1];
      }
    }
    if (t + 2 < nt) {
      stage(A, curA, row0, 0, t + 2);
      stage(Bt, curB, col0, 0, t + 2);
    }
    __builtin_amdgcn_s_barrier();
    __builtin_amdgcn_s_setprio(1);
#pragma unroll
    for (int ks = 0; ks < 2; ++ks)
#pragma unroll
      for (int mi = 0; mi < 4; ++mi)
#pragma unroll
        for (int ni = 0; ni < 2; ++ni) {
          acc[2][mi][ni] = __builtin_amdgcn_mfma_f32_16x16x32_bf16(af[mi][ks], bfr[0][ni][ks], acc[2][mi][ni], 0, 0, 0);
          acc[3][mi][ni] = __builtin_amdgcn_mfma_f32_16x16x32_bf16(af[mi][ks], bfr[1][ni][ks], acc[3][mi][ni], 0, 0, 0);
        }
    __builtin_amdgcn_s_setprio(0);
    if (t < nt - 2)       asm volatile("s_waitcnt vmcnt(6)" ::: "memory");  // lo(t+1)+B-hi(t+1) landed
    else if (t == nt - 2) asm volatile("s_waitcnt vmcnt(2)" ::: "memory");  // tail
    __builtin_amdgcn_s_barrier();
  }

#pragma unroll
  for (int q = 0; q < 4; ++q) {
    const int ah = q >> 1, bh = q & 1;
#pragma unroll
    for (int mi = 0; mi < 4; ++mi)
#pragma unroll
      for (int ni = 0; ni < 2; ++ni)
#pragma unroll
        for (int j = 0; j < 4; ++j) {
          const int row = row0 + ah * 128 + wm * 64 + mi * 16 + lh * 4 + j;
          const int col = col0 + bh * 128 + wn * 32 + ni * 16 + lq;
          storeC(C, (size_t)row * N + col, acc[q][mi][ni][j]);
        }
  }
}

// ---------------- RoPE (NeoX), in-place on qkv; folds scale*log2e into q ----------------
__global__ void rope_kernel(u16* __restrict__ qkv, const int* __restrict__ pos, float qscale) {
  __shared__ float cs[64], sn[64];
  const int row = blockIdx.x;
  const int tid = threadIdx.x;
  if (tid < 64) {
    float p = (float)pos[row];
    float inv = exp2f(-(float)tid * 0.20762050593046f);
    float a = p * inv;
    cs[tid] = cosf(a);
    sn[tid] = sinf(a);
  }
  __syncthreads();
  const size_t base = (size_t)row * QKV_N;
  for (int i = tid; i < 40 * 64; i += 256) {
    const int h = i >> 6, d = i & 63;
    const size_t o = base + h * 128 + d;
    float x1 = b2f(qkv[o]), x2 = b2f(qkv[o + 64]);
    float c = cs[d], s = sn[d];
    float o1 = x1 * c - x2 * s;
    float o2 = x2 * c + x1 * s;
    if (h < NH) { o1 *= qscale; o2 *= qscale; }
    qkv[o] = f2b(o1);
    qkv[o + 64] = f2b(o2);
  }
}

// ---------------- V transpose: qkv v-section -> vt[(b*8+kvh)*128 + d][2048] ----------------
__global__ void v_transpose(const u16* __restrict__ qkv, u16* __restrict__ vt) {
  __shared__ u16 t[32][33];
  const int b = blockIdx.z >> 3, kvh = blockIdx.z & 7;
  const int s0 = blockIdx.x * 32, d0 = blockIdx.y * 32;
  const int tx = threadIdx.x, ty = threadIdx.y;
#pragma unroll
  for (int i = 0; i < 4; ++i)
    t[ty + i * 8][tx] = qkv[(size_t)(b * SEQ + s0 + ty + i * 8) * QKV_N + 5120 + kvh * 128 + d0 + tx];
  __syncthreads();
#pragma unroll
  for (int i = 0; i < 4; ++i)
    vt[(size_t)((b * NKV + kvh) * HD + d0 + ty + i * 8) * SEQ + s0 + tx] = t[tx][ty + i * 8];
}

// ---------------- Flash attention: 8 waves x 32 q-rows, 32x32x16 MFMA, swapped QK^T ----------------
__global__ __launch_bounds__(512, 2) void attn_kernel(const u16* __restrict__ qkv, const u16* __restrict__ vt,
                                                      u16* __restrict__ attn) {
  __shared__ __align__(16) u16 sK[2][64 * 128];   // [kv][d]
  __shared__ __align__(16) u16 sV[2][128 * 64];   // [d][kv]
  const int b = blockIdx.z, h = blockIdx.y;
  const int qt = (b == 0) ? blockIdx.x : 7 - blockIdx.x;  // anti-correlated pairing for balance
  const int kvh = h >> 2;
  const int qb = qt * 256;
  const int tid = threadIdx.x, w = tid >> 6, lane = tid & 63;
  const int lq = lane & 31, hi = lane >> 5, x7 = lane & 7;
  const int qw = qb + (w << 5);
  const int qa = qw + lq;
  const int nt = 4 * (qt + 1);

  auto stage = [&](int buf, int kt) {
    const int k0 = kt * 64;
#pragma unroll
    for (int c = 0; c < 2; ++c) {
      const int g = c * 512 + tid;
      const int r = g >> 4, gc = g & 15;
      const int gs = gc ^ (r & 7);
      gload16(qkv + (size_t)(b * SEQ + k0 + r) * QKV_N + 4096 + kvh * 128 + gs * 8,
              &sK[buf][(c * 512 + (w << 6)) * 8]);
    }
#pragma unroll
    for (int c = 0; c < 2; ++c) {
      const int g = c * 512 + tid;
      const int r = g >> 3, gc = g & 7;
      const int gs = gc ^ (r & 7);
      gload16(vt + (size_t)((b * NKV + kvh) * HD + r) * SEQ + k0 + gs * 8,
              &sV[buf][(c * 512 + (w << 6)) * 8]);
    }
  };

  stage(0, 0);
  bf16x8 qf[8];
#pragma unroll
  for (int ks = 0; ks < 8; ++ks)
    qf[ks] = *(const bf16x8*)&qkv[(size_t)(b * SEQ + qw + lq) * QKV_N + h * 128 + ks * 16 + 8 * hi];

  f32x16 o[4] = {};
  float mreg = -1e30f, lreg = 0.f;

  asm volatile("s_waitcnt vmcnt(0)" ::: "memory");
  __builtin_amdgcn_s_barrier();

  for (int kt = 0; kt < nt; ++kt) {
    const int cur = kt & 1;
    const int k0 = kt * 64;
    if (kt + 1 < nt) {
      stage(cur ^ 1, kt + 1);
      asm volatile("s_waitcnt vmcnt(4)" ::: "memory");
    } else {
      asm volatile("s_waitcnt vmcnt(0)" ::: "memory");
    }
    __builtin_amdgcn_s_barrier();

    if (k0 <= qw + 31) {  // wave-active (causal skip)
      const u16* sk = sK[cur];
      f32x16 st0 = {}, st1 = {};
      __builtin_amdgcn_s_setprio(1);
#pragma unroll
      for (int ks = 0; ks < 8; ++ks) {
        const int g = ((2 * ks + hi) ^ x7) * 8;
        bf16x8 kf0 = *(const bf16x8*)&sk[lq * 128 + g];
        bf16x8 kf1 = *(const bf16x8*)&sk[(32 + lq) * 128 + g];
        st0 = __builtin_amdgcn_mfma_f32_32x32x16_bf16(kf0, qf[ks], st0, 0, 0, 0);
        st1 = __builtin_amdgcn_mfma_f32_32x32x16_bf16(kf1, qf[ks], st1, 0, 0, 0);
      }
      __builtin_amdgcn_s_setprio(0);
      if (k0 + 63 > qw) {
#pragma unroll
        for (int r = 0; r < 16; ++r) {
          const int cr = (r & 3) + 8 * (r >> 2) + 4 * hi;
          st0[r] = (k0 + cr <= qa) ? st0[r] : -1e30f;
          st1[r] = (k0 + 32 + cr <= qa) ? st1[r] : -1e30f;
        }
      }
      float a8[8];
#pragma unroll
      for (int r = 0; r < 8; ++r)
        a8[r] = fmaxf(fmaxf(st0[r], st0[r + 8]), fmaxf(st1[r], st1[r + 8]));
#pragma unroll
      for (int s = 4; s; s >>= 1)
#pragma unroll
        for (int r = 0; r < s; ++r) a8[r] = fmaxf(a8[r], a8[r + s]);
      const float pm = pl_partner_max(a8[0]);
      if (!__all(pm <= mreg + 8.f)) {
        const float mn = fmaxf(mreg, pm);
        const float al = exp2f(mreg - mn);
        lreg *= al;
        mreg = mn;
#pragma unroll
        for (int r = 0; r < 16; ++r) {
          const int cr = (r & 3) + 8 * (r >> 2) + 4 * hi;
          const float ar = __shfl(al, cr, 64);
#pragma unroll
          for (int dn = 0; dn < 4; ++dn) o[dn][r] *= ar;
        }
      }
#pragma unroll
      for (int r = 0; r < 16; ++r) {
        st0[r] = exp2f(st0[r] - mreg);
        st1[r] = exp2f(st1[r] - mreg);
      }
      float s8[8];
#pragma unroll
      for (int r = 0; r < 8; ++r)
        s8[r] = (st0[r] + st0[r + 8]) + (st1[r] + st1[r + 8]);
#pragma unroll
      for (int s = 4; s; s >>= 1)
#pragma unroll
        for (int r = 0; r < s; ++r) s8[r] += s8[r + s];
      lreg += pl_partner_sum(s8[0]);
      union U8 { unsigned w[4]; bf16x8 v; };
      U8 pa[4];
#define PACKFRAG(F, P0, P1, P2, P3, P4, P5, P6, P7)                   \
      {                                                               \
        unsigned a0 = pk(P0, P1), a1 = pk(P2, P3);                    \
        unsigned b0 = pk(P4, P5), b1 = pk(P6, P7);                    \
        plswap(a0, b0); plswap(a1, b1);                               \
        pa[F].w[0] = a0; pa[F].w[1] = a1; pa[F].w[2] = b0; pa[F].w[3] = b1; \
      }
      PACKFRAG(0, st0[0], st0[1], st0[2], st0[3], st0[4], st0[5], st0[6], st0[7])
      PACKFRAG(1, st0[8], st0[9], st0[10], st0[11], st0[12], st0[13], st0[14], st0[15])
      PACKFRAG(2, st1[0], st1[1], st1[2], st1[3], st1[4], st1[5], st1[6], st1[7])
      PACKFRAG(3, st1[8], st1[9], st1[10], st1[11], st1[12], st1[13], st1[14], st1[15])
#undef PACKFRAG
      const u16* sv = sV[cur];
      __builtin_amdgcn_s_setprio(1);
#pragma unroll
      for (int dn = 0; dn < 4; ++dn) {
#pragma unroll
        for (int ks = 0; ks < 4; ++ks) {
          bf16x8 vf = *(const bf16x8*)&sv[(dn * 32 + lq) * 64 + (((2 * ks + hi) ^ x7)) * 8];
          o[dn] = __builtin_amdgcn_mfma_f32_32x32x16_bf16(pa[ks].v, vf, o[dn], 0, 0, 0);
        }
      }
      __builtin_amdgcn_s_setprio(0);
    }
    __builtin_amdgcn_s_barrier();
  }

  const float inv = 1.0f / lreg;
#pragma unroll
  for (int r = 0; r < 16; ++r) {
    const int cr = (r & 3) + 8 * (r >> 2) + 4 * hi;
    const float fr = __shfl(inv, cr, 64);
    const size_t row = (size_t)(b * SEQ + qw + cr);
#pragma unroll
    for (int dn = 0; dn < 4; ++dn)
      attn[row * 4096 + h * 128 + dn * 32 + lq] = f2b(o[dn][r] * fr);
  }
}

extern "C" void kernel_launch(void* const* d_in, const int* in_sizes, int n_in,
                              void* d_out, int out_size, void* d_ws, size_t ws_size,
                              hipStream_t stream) {
  const float* hs = (const float*)d_in[0];
  const int* pos = (const int*)d_in[1];
  const float* w_qkv = (const float*)d_in[2];
  const float* w_o = (const float*)d_in[3];
  float* out = (float*)d_out;
  char* ws = (char*)d_ws;

  u16* hid = (u16*)ws;                        // 4096*4096 bf16 = 32 MiB
  u16* attnb = hid;                           // reused after qkv GEMM consumes hid
  u16* wT = (u16*)(ws + 33554432);            // up to 6144*4096 bf16 = 48 MiB
  u16* qkv = (u16*)(ws + 83886080);           // 4096*6144 bf16 = 48 MiB
  u16* vt = (u16*)(ws + 134217728);           // 2*8*128*2048 bf16 = 8 MiB

  const float qscale = 0.12751744f;  // (1/sqrt(128)) * log2(e)

  cast_f32_bf16<<<16384, 256, 0, stream>>>(hs, hid, 4096 * 4096);
  cast_transpose<<<dim3(192, 128), dim3(32, 8), 0, stream>>>(w_qkv, wT, 4096, QKV_N);
  gemm256<u16><<<384, 512, 0, stream>>>(hid, wT, qkv, 4096, QKV_N, 4096);
  rope_kernel<<<4096, 256, 0, stream>>>(qkv, pos, qscale);
  v_transpose<<<dim3(64, 4, 16), dim3(32, 8), 0, stream>>>(qkv, vt);
  cast_transpose<<<dim3(128, 128), dim3(32, 8), 0, stream>>>(w_o, wT, 4096, 4096);
  attn_kernel<<<dim3(8, 32, 2), 512, 0, stream>>>(qkv, vt, attnb);
  gemm256<float><<<256, 512, 0, stream>>>(attnb, wT, out, 4096, 4096, 4096);
}